// Round 1
// baseline (4105.293 us; speedup 1.0000x reference)
//
#include <hip/hip_runtime.h>

#define SEQ   1024
#define DIN   64
#define NHID  256
#define NBLK  64
#define NTHR  512
#define MR    16
#define KT_H  8
#define KT_X  2

typedef _Float16 f16x8 __attribute__((ext_vector_type(8)));
typedef float    f32x4 __attribute__((ext_vector_type(4)));

#define MFMA16(a,b,c) __builtin_amdgcn_mfma_f32_16x16x32_f16((a),(b),(c),0,0,0)

__device__ __forceinline__ float sigm(float v)  { return 1.f/(1.f + __expf(-v)); }
__device__ __forceinline__ float tanh_f(float v){ return 1.f - 2.f/(__expf(2.f*v)+1.f); }

__device__ __forceinline__ f16x8 cvt8(f32x4 a, f32x4 b){
  f16x8 r;
  r[0]=(_Float16)a[0]; r[1]=(_Float16)a[1]; r[2]=(_Float16)a[2]; r[3]=(_Float16)a[3];
  r[4]=(_Float16)b[0]; r[5]=(_Float16)b[1]; r[6]=(_Float16)b[2]; r[7]=(_Float16)b[3];
  return r;
}

// 64 blocks = 16 groups (16 batch rows each) x 4 members (64 hidden cols each).
// Group members {g, g+16, g+32, g+48} are congruent mod 8 -> same XCD L2.
__global__ void __launch_bounds__(NTHR, 2)
lstm_seq(const float* __restrict__ x, const float* __restrict__ h0,
         const float* __restrict__ c0, const float* __restrict__ Wi,
         const float* __restrict__ bi, const float* __restrict__ Wh,
         const float* __restrict__ bh, const float* __restrict__ Wcls,
         int* __restrict__ flags, unsigned int* __restrict__ slices,
         float* __restrict__ partial)
{
  __shared__ __align__(16) unsigned int h_lds[MR*128];  // 16 rows x 256 f16 (as u32 pairs)
  __shared__ __align__(16) float g_lds[MR*256];         // gate preacts, block-local cols
  __shared__ __align__(16) float c_lds[MR*64];          // cell state (own 64 cols)
  __shared__ __align__(16) float bias_lds[256];         // bi+bh for own cols, [gate*64+jl]

  const int bid = blockIdx.x;
  const int grp = bid & 15;   // batch group
  const int q   = bid >> 4;   // member 0..3 (hidden col quarter)
  const int tid = threadIdx.x;
  const int w   = tid >> 6;
  const int l   = tid & 63;
  const int l15 = l & 15;
  const int lhi = l >> 4;

  // ---- weight fragments, register-resident (f16) ----
  // wave w owns n-tiles nt = 2w, 2w+1 of 16; nt -> gate = nt>>2, colblk = nt&3.
  f16x8 wh[2][KT_H], wi[2][KT_X];
  #pragma unroll
  for (int t=0;t<2;t++){
    const int nt    = w*2 + t;
    const int gamma = nt >> 2, cb = nt & 3;
    const int row   = gamma*256 + q*64 + cb*16 + l15;   // row of Wi/Wh (gate output)
    #pragma unroll
    for (int kt=0;kt<KT_H;kt++){
      const float* p = Wh + row*NHID + kt*32 + lhi*8;
      wh[t][kt] = cvt8(*(const f32x4*)p, *(const f32x4*)(p+4));
    }
    #pragma unroll
    for (int kt=0;kt<KT_X;kt++){
      const float* p = Wi + row*DIN + kt*32 + lhi*8;
      wi[t][kt] = cvt8(*(const f32x4*)p, *(const f32x4*)(p+4));
    }
  }

  if (tid < 256){
    const int gamma = tid>>6, jl = tid&63;
    const int jg = gamma*256 + q*64 + jl;
    bias_lds[tid] = bi[jg] + bh[jg];
  }
  // h0 -> h_lds (f16), c0 -> c_lds (f32, own quarter)
  for (int i=tid; i<MR*128; i+=NTHR){
    const int b = i>>7, c2 = i&127;
    union { _Float16 h[2]; unsigned int u; } pk;
    pk.h[0] = (_Float16)h0[(grp*16+b)*NHID + c2*2];
    pk.h[1] = (_Float16)h0[(grp*16+b)*NHID + c2*2 + 1];
    h_lds[i] = pk.u;
  }
  for (int i=tid; i<MR*64; i+=NTHR){
    const int b = i>>6, jl = i&63;
    c_lds[i] = c0[(grp*16+b)*NHID + q*64 + jl];
  }
  __syncthreads();

  // x prefetch (row = batch row l15 of this group's 16)
  const float* xrow = x + (size_t)(grp*16 + l15) * (SEQ*DIN);
  f32x4 xp0,xp1,xp2,xp3;
  {
    const float* p = xrow + lhi*8;
    xp0 = *(const f32x4*)p;      xp1 = *(const f32x4*)(p+4);
    xp2 = *(const f32x4*)(p+32); xp3 = *(const f32x4*)(p+36);
  }

  const int flag_self = (grp*4 + q)*16;

  for (int s=0; s<SEQ; s++){
    f32x4 acc0 = {0.f,0.f,0.f,0.f}, acc1 = {0.f,0.f,0.f,0.f};
    // input projection for step s (x prefetched last iter)
    {
      f16x8 ax0 = cvt8(xp0, xp1);
      f16x8 ax1 = cvt8(xp2, xp3);
      acc0 = MFMA16(ax0, wi[0][0], acc0);
      acc0 = MFMA16(ax1, wi[0][1], acc0);
      acc1 = MFMA16(ax0, wi[1][0], acc1);
      acc1 = MFMA16(ax1, wi[1][1], acc1);
    }
    // prefetch x for step s+1 (hidden under the MFMA chain below)
    {
      const int sn = (s < SEQ-1) ? s+1 : s;
      const float* p = xrow + sn*DIN + lhi*8;
      xp0 = *(const f32x4*)p;      xp1 = *(const f32x4*)(p+4);
      xp2 = *(const f32x4*)(p+32); xp3 = *(const f32x4*)(p+36);
    }
    // recurrent projection: A from h_lds, B register-resident
    const _Float16* hp = (const _Float16*)h_lds;
    #pragma unroll
    for (int kt=0; kt<KT_H; kt++){
      f16x8 a = *(const f16x8*)(hp + l15*256 + kt*32 + lhi*8);
      acc0 = MFMA16(a, wh[0][kt], acc0);
      acc1 = MFMA16(a, wh[1][kt], acc1);
    }
    __syncthreads();   // all h_lds reads done before pointwise rewrites it; g_lds reusable
    {
      const int nt0 = w*2;
      #pragma unroll
      for (int r=0;r<4;r++){    // C/D map: col = l&15, row = (l>>4)*4 + r  [m89]
        g_lds[(lhi*4+r)*256 +  nt0   *16 + l15] = acc0[r];
        g_lds[(lhi*4+r)*256 + (nt0+1)*16 + l15] = acc1[r];
      }
    }
    __syncthreads();
    // pointwise gates: 1024 (b,jl) pairs, 2 per thread
    {
      const int b = tid>>5, i2 = tid&31;
      union { _Float16 h[2]; unsigned int u; } pk;
      #pragma unroll
      for (int u2=0; u2<2; u2++){
        const int jl = i2*2 + u2;
        const float gf = g_lds[b*256 +       jl] + bias_lds[      jl];
        const float gi = g_lds[b*256 +  64 + jl] + bias_lds[ 64 + jl];
        const float gc = g_lds[b*256 + 128 + jl] + bias_lds[128 + jl];
        const float go = g_lds[b*256 + 192 + jl] + bias_lds[192 + jl];
        const float f  = sigm(gf);
        const float ii = sigm(gi);
        const float gt = tanh_f(gc);
        const float oo = sigm(go);
        const float cn = c_lds[b*64 + jl]*f + ii*gt;
        c_lds[b*64 + jl] = cn;
        pk.h[u2] = (_Float16)(tanh_f(cn)*oo);
      }
      h_lds[b*128 + q*32 + i2] = pk.u;   // own quarter of next h
      // publish own slice (parity-double-buffered), L1-bypassing
      __hip_atomic_store(slices + ((size_t)(s&1)*NBLK + grp*4 + q)*512 + tid, pk.u,
                         __ATOMIC_RELAXED, __HIP_MEMORY_SCOPE_AGENT);
    }
    __syncthreads();   // slice stores drained (vmcnt) before flag release
    if (tid == 0)
      __hip_atomic_store(&flags[flag_self], s+1, __ATOMIC_RELEASE, __HIP_MEMORY_SCOPE_AGENT);
    if (s < SEQ-1){
      if (tid < 3){
        const int qq = tid + (tid >= q);
        while (__hip_atomic_load(&flags[(grp*4+qq)*16], __ATOMIC_ACQUIRE,
                                 __HIP_MEMORY_SCOPE_AGENT) < s+1) {}
      }
      __syncthreads();
      {
        const int b = tid>>5, i2 = tid&31;   // tid == b*32+i2 == slice word index
        #pragma unroll
        for (int dq=1; dq<4; dq++){
          const int qq = (q+dq)&3;
          unsigned int v = __hip_atomic_load(
              slices + ((size_t)(s&1)*NBLK + grp*4 + qq)*512 + tid,
              __ATOMIC_RELAXED, __HIP_MEMORY_SCOPE_AGENT);
          h_lds[b*128 + qq*32 + i2] = v;
        }
      }
      __syncthreads();
    }
  }

  // classifier partials on own 64 hidden cols
  if (tid < 160){
    const int b = tid/10, j = tid - b*10;
    const _Float16* hp = (const _Float16*)h_lds;
    float sum = 0.f;
    for (int k=0;k<64;k++)
      sum += Wcls[j*NHID + q*64 + k] * (float)hp[b*256 + q*64 + k];
    partial[(size_t)q*2560 + (grp*16+b)*10 + j] = sum;
  }
}

__global__ void lstm_out(const float* __restrict__ bcls,
                         const float* __restrict__ partial,
                         float* __restrict__ out){
  const int i = blockIdx.x*256 + threadIdx.x;
  if (i < 2560){
    float s = bcls[i % 10];
    #pragma unroll
    for (int qq=0;qq<4;qq++) s += partial[(size_t)qq*2560 + i];
    out[i] = s;
  }
}

extern "C" void kernel_launch(void* const* d_in, const int* in_sizes, int n_in,
                              void* d_out, int out_size, void* d_ws, size_t ws_size,
                              hipStream_t stream){
  const float* x    = (const float*)d_in[0];
  const float* h0   = (const float*)d_in[1];
  const float* c0   = (const float*)d_in[2];
  const float* Wi   = (const float*)d_in[3];
  const float* bi   = (const float*)d_in[4];
  const float* Wh   = (const float*)d_in[5];
  const float* bh   = (const float*)d_in[6];
  const float* Wcls = (const float*)d_in[7];
  const float* bcls = (const float*)d_in[8];

  char* ws = (char*)d_ws;
  int*          flags   = (int*)ws;                     // 64 flags, 64B apart: 4096 B
  unsigned int* slices  = (unsigned int*)(ws + 4096);   // 2 x 64 x 512 u32 = 262144 B
  float*        partial = (float*)(ws + 4096 + 262144); // 4 x 2560 f32 = 40960 B

  hipMemsetAsync(flags, 0, 4096, stream);  // flags must start at 0 every call
  hipLaunchKernelGGL(lstm_seq, dim3(NBLK), dim3(NTHR), 0, stream,
                     x, h0, c0, Wi, bi, Wh, bh, Wcls, flags, slices, partial);
  hipLaunchKernelGGL(lstm_out, dim3(10), dim3(256), 0, stream,
                     bcls, partial, (float*)d_out);
}